// Round 4
// baseline (625.393 us; speedup 1.0000x reference)
//
#include <hip/hip_runtime.h>
#include <math.h>

typedef unsigned long long u64;

#define BATCH 16
#define NBOX 100000
#define NCLS 30
#define K 200            // PRE_NMS_TOPK
#define MAXDET 100
#define SCORE_THR 0.01f
#define NMS_THR 0.5f
#define T0 0.995f        // static collect threshold; fallback guarantees exactness

#define ELEM_PER_BATCH (NBOX * NCLS)              // 3,000,000
#define CAP 1024

// workspace layout (bytes)
#define OFF_COLL   0ull                                            // u64[480*CAP]
#define OFF_CNT    (OFF_COLL + (size_t)BATCH*NCLS*CAP*8)           // int[480]
#define OFF_WSS    (OFF_CNT + 480*4)                               // float[480*200] (fallback only)
#define OFF_WSI    (OFF_WSS + (size_t)BATCH*NCLS*K*4)              // int[480*200]
#define OFF_MERGE  (OFF_WSI + (size_t)BATCH*NCLS*K*4)              // u64[16][32][128]

// ---------------------------------------------------------------------------
// 0) Zero the per-(b,c) counters.
// ---------------------------------------------------------------------------
__global__ __launch_bounds__(512) void init_kernel(int* __restrict__ cnt) {
  if (threadIdx.x < BATCH * NCLS) cnt[threadIdx.x] = 0;
}

// ---------------------------------------------------------------------------
// 1) Single coalesced pass: collect all entries > T0 with their class/index.
//    Grid-stride, 2048x256: deep MLP, non-hit path is 4 compares per float4.
// ---------------------------------------------------------------------------
__global__ __launch_bounds__(256) void collect_kernel(const float* __restrict__ cls,
                                                      int* __restrict__ cnt,
                                                      u64* __restrict__ coll) {
  const int nvec_total = (BATCH * ELEM_PER_BATCH) / 4;   // 12,000,000
  for (int i = blockIdx.x * 256 + threadIdx.x; i < nvec_total; i += gridDim.x * 256) {
    float4 v = ((const float4*)cls)[i];
    float vv[4] = {v.x, v.y, v.z, v.w};
    #pragma unroll
    for (int j = 0; j < 4; ++j) {
      float f = vv[j];
      if (f > T0) {                     // rare (~0.5%)
        int et = i * 4 + j;             // global element index (< 48M, fits int)
        int b  = et / ELEM_PER_BATCH;
        int ej = et - b * ELEM_PER_BATCH;
        int c  = ej % NCLS;
        int n  = ej / NCLS;
        int bc = b * NCLS + c;
        int pos = atomicAdd(&cnt[bc], 1);
        if (pos < CAP)
          coll[(size_t)bc * CAP + pos] =
            ((u64)__float_as_uint(f) << 32) | (unsigned)(~(unsigned)n);
      }
    }
  }
}

// ---------------------------------------------------------------------------
// 2) Exact radix-select fallback for (b,c) with cnt<K or cnt>CAP.
//    Normally a no-op on every block.
// ---------------------------------------------------------------------------
__global__ __launch_bounds__(1024) void fallback_kernel(const float* __restrict__ cls,
                                                        const int* __restrict__ cnt,
                                                        float* __restrict__ ws_s,
                                                        int* __restrict__ ws_i) {
  const int bc = blockIdx.x;
  {
    int ct = cnt[bc];
    if (ct >= K && ct <= CAP) return;   // healthy: handled by fused kernel
  }
  const int b = bc / NCLS, c = bc % NCLS;
  const int tid = threadIdx.x;
  const int nth = blockDim.x;
  const int wv = tid >> 6;

  __shared__ unsigned hist[16][256];
  __shared__ u64 comb[256];
  __shared__ unsigned eqbuf[512];
  __shared__ unsigned s_pref, s_mask, s_krem, s_takeall;
  __shared__ unsigned s_cntgt, s_cnteq;

  if (tid == 0) { s_pref = 0u; s_mask = 0u; s_krem = K; s_takeall = 0u; }
  __syncthreads();
  const float* col = cls + (size_t)b * NBOX * NCLS + c;

  for (int pass = 0; pass < 4; ++pass) {
    if (s_takeall) break;
    const int shift = 24 - 8 * pass;
    for (int i = tid; i < 16 * 256; i += nth) ((unsigned*)hist)[i] = 0u;
    __syncthreads();
    const unsigned pref = s_pref, mask = s_mask;
    for (int n = tid; n < NBOX; n += nth) {
      float v = col[(size_t)n * NCLS];
      if (v > SCORE_THR) {
        unsigned key = __float_as_uint(v);
        if ((key & mask) == pref)
          atomicAdd(&hist[wv][(key >> shift) & 0xFFu], 1u);
      }
    }
    __syncthreads();
    if (tid < 256) {
      unsigned t2 = 0;
      for (int w = 0; w < 16; ++w) t2 += hist[w][tid];
      hist[0][tid] = t2;
    }
    __syncthreads();
    if (tid == 0) {
      unsigned krem = s_krem, cum = 0; int dsel = -1;
      for (int d = 255; d >= 0; --d) {
        unsigned cc = hist[0][d];
        if (cum + cc >= krem) { dsel = d; break; }
        cum += cc;
      }
      if (dsel < 0) s_takeall = 1u;
      else {
        s_krem = krem - cum;
        s_pref = pref | ((unsigned)dsel << shift);
        s_mask = mask | (0xFFu << shift);
      }
    }
    __syncthreads();
  }

  if (tid == 0) { s_cntgt = 0u; s_cnteq = 0u; }
  __syncthreads();
  const unsigned pivot = s_pref;
  const unsigned takeall = s_takeall;

  for (int n = tid; n < NBOX; n += nth) {
    float v = col[(size_t)n * NCLS];
    if (v > SCORE_THR) {
      unsigned key = __float_as_uint(v);
      if (takeall || key > pivot) {
        unsigned pos = atomicAdd(&s_cntgt, 1u);
        if (pos < 256u)
          comb[pos] = ((u64)key << 32) | (unsigned)(~(unsigned)n);
      } else if (key == pivot) {
        unsigned pos = atomicAdd(&s_cnteq, 1u);
        if (pos < 512u) eqbuf[pos] = (unsigned)n;
      }
    }
  }
  __syncthreads();
  const unsigned cntgt = (s_cntgt < 256u) ? s_cntgt : 256u;
  const unsigned cnteq = (s_cnteq < 512u) ? s_cnteq : 512u;
  unsigned need = 0;
  if (!takeall) {
    need = (cntgt < (unsigned)K) ? ((unsigned)K - cntgt) : 0u;
    if (need > cnteq) need = cnteq;
  }
  for (int i = tid; i < 512; i += nth)
    if ((unsigned)i >= cnteq) eqbuf[i] = 0xFFFFFFFFu;
  for (int k = 2; k <= 512; k <<= 1) {
    for (int j = k >> 1; j > 0; j >>= 1) {
      __syncthreads();
      if (tid < 512) {
        int i = tid, l = i ^ j;
        if (l > i) {
          unsigned a = eqbuf[i], bb = eqbuf[l];
          bool up = ((i & k) == 0);
          if (up ? (a > bb) : (a < bb)) { eqbuf[i] = bb; eqbuf[l] = a; }
        }
      }
    }
  }
  __syncthreads();
  for (int t = tid; t < (int)need; t += nth)
    comb[cntgt + t] = ((u64)pivot << 32) | (unsigned)(~eqbuf[t]);
  const unsigned M = cntgt + need;
  for (int i = tid; i < 256; i += nth)
    if ((unsigned)i >= M) comb[i] = 0ull;
  for (int k = 2; k <= 256; k <<= 1) {
    for (int j = k >> 1; j > 0; j >>= 1) {
      __syncthreads();
      if (tid < 256) {
        int i = tid, l = i ^ j;
        if (l > i) {
          u64 a = comb[i], bb = comb[l];
          bool up = ((i & k) == 0);
          if (up ? (a < bb) : (a > bb)) { comb[i] = bb; comb[l] = a; }
        }
      }
    }
  }
  __syncthreads();
  if (tid < K) {
    if ((unsigned)tid < M) {
      u64 e = comb[tid];
      ws_s[bc * K + tid] = __uint_as_float((unsigned)(e >> 32));
      ws_i[bc * K + tid] = (int)(~(unsigned)e);
    } else {
      ws_s[bc * K + tid] = -INFINITY;
      ws_i[bc * K + tid] = 0;
    }
  }
}

// ---------------------------------------------------------------------------
// 3) Fused: sort candidates -> top-200 -> bitmask NMS -> stable compaction ->
//    emit sorted per-class key list (top-128) for the merge tournament.
// ---------------------------------------------------------------------------
__global__ __launch_bounds__(512) void fused_sort_nms_kernel(
    const u64* __restrict__ coll, const int* __restrict__ cnt,
    const float* __restrict__ ws_s_fb, const int* __restrict__ ws_i_fb,
    const float* __restrict__ boxes,
    int* __restrict__ ws_i, u64* __restrict__ merged) {
  const int bc = blockIdx.x;
  const int b = bc / NCLS, c = bc % NCLS;
  const int tid = threadIdx.x;

  __shared__ u64 arr[CAP];
  __shared__ float sx1[K], sy1[K], sx2[K], sy2[K], sarea[K], ss[K];
  __shared__ int sidx[K];
  __shared__ unsigned mask[K][8];
  __shared__ unsigned keepw[8];
  __shared__ int s_surv;

  const int ct = cnt[bc];
  const bool bad = (ct < K) || (ct > CAP);
  if (!bad) {
    for (int i = tid; i < CAP; i += 512)
      arr[i] = (i < ct) ? coll[(size_t)bc * CAP + i] : 0ull;
    for (int k = 2; k <= CAP; k <<= 1) {
      for (int j = k >> 1; j > 0; j >>= 1) {
        __syncthreads();
        for (int i = tid; i < CAP; i += 512) {
          int l = i ^ j;
          if (l > i) {
            u64 a = arr[i], bb = arr[l];
            bool up = ((i & k) == 0);
            if (up ? (a < bb) : (a > bb)) { arr[i] = bb; arr[l] = a; }
          }
        }
      }
    }
    __syncthreads();
    for (int r = tid; r < K; r += 512) {
      u64 e = arr[r];
      float s = (e != 0ull) ? __uint_as_float((unsigned)(e >> 32)) : -INFINITY;
      int idx = (e != 0ull) ? (int)(~(unsigned)e) : 0;
      ss[r] = s; sidx[r] = idx;
      ws_i[bc * K + r] = idx;
    }
  } else {
    for (int r = tid; r < K; r += 512) {
      ss[r] = ws_s_fb[bc * K + r];
      sidx[r] = ws_i_fb[bc * K + r];
    }
  }
  for (int i = tid; i < K * 8; i += 512) ((unsigned*)mask)[i] = 0u;
  if (tid < 8) keepw[tid] = 0u;
  __syncthreads();

  for (int r = tid; r < K; r += 512) {
    float s = ss[r];
    bool valid = (s != -INFINITY);
    float x1 = 0.f, y1 = 0.f, x2 = 0.f, y2 = 0.f;
    if (valid) {
      const float* bp = boxes + ((size_t)b * NBOX + sidx[r]) * 4;
      x1 = bp[0]; y1 = bp[1]; x2 = bp[2]; y2 = bp[3];
      atomicOr(&keepw[r >> 5], 1u << (r & 31));
    }
    sx1[r] = x1; sy1[r] = y1; sx2[r] = x2; sy2[r] = y2;
    sarea[r] = fmaxf(x2 - x1, 0.f) * fmaxf(y2 - y1, 0.f);
  }
  __syncthreads();

  // pairwise suppression bitmask, j > i (fully parallel, no barriers)
  for (int t = tid; t < K * K; t += 512) {
    int i = t / K, j = t - i * K;
    if (j > i) {
      float xx1 = fmaxf(sx1[i], sx1[j]);
      float yy1 = fmaxf(sy1[i], sy1[j]);
      float xx2 = fminf(sx2[i], sx2[j]);
      float yy2 = fminf(sy2[i], sy2[j]);
      float inter = fmaxf(xx2 - xx1, 0.f) * fmaxf(yy2 - yy1, 0.f);
      float uni = sarea[i] + sarea[j] - inter;
      float iou = inter / fmaxf(uni, 1e-8f);
      if (iou > NMS_THR) atomicOr(&mask[i][j >> 5], 1u << (j & 31));
    }
  }
  __syncthreads();

  // serial greedy scan on wave 0 (wave-synchronous, no barriers)
  if (tid < 64) {
    int w = tid & 7;
    unsigned keep = keepw[w];
    for (int i = 0; i < K; ++i) {
      unsigned kw = __shfl(keep, i >> 5, 64);
      if ((kw >> (i & 31)) & 1u)
        keep &= ~mask[i][w];
    }
    if (tid < 8) keepw[tid] = keep;
  }
  __syncthreads();

  // stable compaction + key emission (per-class list is sorted desc by key)
  for (int r = tid; r < K; r += 512) {
    int w6 = r >> 5, bit = r & 31;
    if ((keepw[w6] >> bit) & 1u) {
      int pos = 0;
      #pragma unroll
      for (int w = 0; w < 7; ++w) {
        unsigned kw = keepw[w];
        if (w < w6) pos += __popc(kw);
        else if (w == w6) pos += __popc(kw & ((1u << bit) - 1u));
      }
      if (pos < 128) {
        unsigned ord = __float_as_uint(ss[r]) | 0x80000000u;
        merged[((size_t)b * 32 + c) * 128 + pos] =
          ((u64)ord << 32) | (unsigned)(~(unsigned)(c * K + r));
      }
    }
  }
  if (tid == 0) {
    int S = 0;
    #pragma unroll
    for (int w = 0; w < 7; ++w) S += __popc(keepw[w]);
    s_surv = S;
  }
  __syncthreads();
  for (int t = s_surv + tid; t < 128; t += 512)
    merged[((size_t)b * 32 + c) * 128 + t] = 0ull;
}

// ---------------------------------------------------------------------------
// 4) Per-image merge tournament: 32 sorted lists of 128 -> top-128 -> gather.
// ---------------------------------------------------------------------------
__global__ __launch_bounds__(1024) void merge_gather_kernel(
    const u64* __restrict__ merged, const int* __restrict__ ws_i,
    const float* __restrict__ boxes, const float* __restrict__ rot,
    const float* __restrict__ tr, float* __restrict__ out) {
  const int b = blockIdx.x;
  const int tid = threadIdx.x;
  __shared__ u64 W[4096];

  for (int t = tid; t < 4096; t += 1024) {
    int c = t >> 7, r = t & 127;
    W[t] = (c < NCLS) ? merged[((size_t)b * 32 + c) * 128 + r] : 0ull;
  }
  __syncthreads();

  int active = 4096;
  #pragma unroll
  for (int level = 0; level < 5; ++level) {
    int npairs = active >> 8;
    for (int t = tid; t < npairs * 64; t += 1024) {
      int p = t >> 6, q = t & 63;
      int i1 = p * 256 + 128 + q, i2 = p * 256 + 255 - q;
      u64 a = W[i1]; W[i1] = W[i2]; W[i2] = a;
    }
    __syncthreads();
    for (int j = 128; j > 0; j >>= 1) {
      for (int i = tid; i < active; i += 1024) {
        int l = i ^ j;
        if (l > i) {
          u64 a = W[i], bb = W[l];
          if (a < bb) { W[i] = bb; W[l] = a; }
        }
      }
      __syncthreads();
    }
    int half = active >> 1;
    u64 t0 = 0, t1 = 0;
    if (tid < half) t0 = W[(tid >> 7) * 256 + (tid & 127)];
    int t2i = tid + 1024;
    if (t2i < half) t1 = W[(t2i >> 7) * 256 + (t2i & 127)];
    __syncthreads();
    if (tid < half) W[tid] = t0;
    if (t2i < half) W[t2i] = t1;
    __syncthreads();
    active = half;
  }

  if (tid < MAXDET) {
    u64 key = W[tid];
    bool valid = (key != 0ull);
    float* ob  = out + ((size_t)b * MAXDET + tid) * 4;
    float* os  = out + (size_t)BATCH * MAXDET * 4 + b * MAXDET + tid;
    float* ol  = os + BATCH * MAXDET;
    float* orr = out + (size_t)BATCH * MAXDET * 6 + ((size_t)b * MAXDET + tid) * 3;
    float* ot  = orr + (size_t)BATCH * MAXDET * 3;

    if (valid) {
      unsigned f = ~(unsigned)key;            // flat = c*K + r
      int cl = (int)(f / K);
      float sc = __uint_as_float((unsigned)(key >> 32) & 0x7FFFFFFFu);
      int orig = ws_i[(size_t)b * NCLS * K + f];
      const float* bp = boxes + ((size_t)b * NBOX + orig) * 4;
      ob[0] = bp[0]; ob[1] = bp[1]; ob[2] = bp[2]; ob[3] = bp[3];
      *os = sc;
      *ol = (float)cl;
      const float* rp = rot + ((size_t)b * NBOX + orig) * 3;
      orr[0] = rp[0]; orr[1] = rp[1]; orr[2] = rp[2];
      const float* tp = tr + ((size_t)b * NBOX + orig) * 3;
      ot[0] = tp[0]; ot[1] = tp[1]; ot[2] = tp[2];
    } else {
      ob[0] = ob[1] = ob[2] = ob[3] = -1.f;
      *os = -1.f; *ol = -1.f;
      orr[0] = orr[1] = orr[2] = -1.f;
      ot[0] = ot[1] = ot[2] = -1.f;
    }
  }
}

extern "C" void kernel_launch(void* const* d_in, const int* in_sizes, int n_in,
                              void* d_out, int out_size, void* d_ws, size_t ws_size,
                              hipStream_t stream) {
  const float* boxes = (const float*)d_in[0];
  const float* cls   = (const float*)d_in[1];
  const float* rot   = (const float*)d_in[2];
  const float* tr    = (const float*)d_in[3];
  float* out = (float*)d_out;

  char* ws = (char*)d_ws;
  u64*   coll   = (u64*)(ws + OFF_COLL);
  int*   cnt    = (int*)(ws + OFF_CNT);
  float* ws_s   = (float*)(ws + OFF_WSS);
  int*   ws_i   = (int*)(ws + OFF_WSI);
  u64*   merged = (u64*)(ws + OFF_MERGE);

  init_kernel<<<1, 512, 0, stream>>>(cnt);
  collect_kernel<<<2048, 256, 0, stream>>>(cls, cnt, coll);
  fallback_kernel<<<BATCH * NCLS, 1024, 0, stream>>>(cls, cnt, ws_s, ws_i);
  fused_sort_nms_kernel<<<BATCH * NCLS, 512, 0, stream>>>(coll, cnt, ws_s, ws_i,
                                                          boxes, ws_i, merged);
  merge_gather_kernel<<<BATCH, 1024, 0, stream>>>(merged, ws_i, boxes, rot, tr, out);
}

// Round 5
// 121.912 us; speedup vs baseline: 5.1299x; 5.1299x over previous
//
#include <hip/hip_runtime.h>
#include <math.h>

typedef unsigned long long u64;

#define BATCH 16
#define NBOX 100000
#define NCLS 30
#define K 200            // PRE_NMS_TOPK
#define MAXDET 100
#define SCORE_THR 0.01f
#define NMS_THR 0.5f
#define T0 0.995f        // static collect threshold; fallback guarantees exactness

#define ELEM_PER_BATCH (NBOX * NCLS)              // 3,000,000
#define CAP 1024
#define CHUNKS 48                                 // chunks per batch
#define VEC_PER_CHUNK 15625                       // 750000 vec4 per batch / 48
#define LDS_CAP 48                                // per-class per-block hit buffer

// workspace layout (bytes)
#define OFF_COLL   0ull                                            // u64[480*CAP]
#define OFF_CNT    (OFF_COLL + (size_t)BATCH*NCLS*CAP*8)           // int[480]
#define OFF_WSS    (OFF_CNT + 480*4)                               // float[480*200] (fallback only)
#define OFF_WSI    (OFF_WSS + (size_t)BATCH*NCLS*K*4)              // int[480*200]
#define OFF_MERGE  (OFF_WSI + (size_t)BATCH*NCLS*K*4)              // u64[16][32][128]

// ---------------------------------------------------------------------------
// 0) Zero the per-(b,c) counters.
// ---------------------------------------------------------------------------
__global__ __launch_bounds__(512) void init_kernel(int* __restrict__ cnt) {
  if (threadIdx.x < BATCH * NCLS) cnt[threadIdx.x] = 0;
}

// ---------------------------------------------------------------------------
// 1) Single coalesced pass: collect entries > T0. Hits staged in per-class
//    LDS buffers (LDS atomics only); ONE global atomicAdd per (class,block)
//    reserves a contiguous segment of coll. No global atomics in the loop.
// ---------------------------------------------------------------------------
__global__ __launch_bounds__(512) void collect_kernel(const float* __restrict__ cls,
                                                      int* __restrict__ cnt,
                                                      u64* __restrict__ coll) {
  const int b = blockIdx.x / CHUNKS;
  const int chunk = blockIdx.x % CHUNKS;
  const int tid = threadIdx.x;

  __shared__ u64 lbuf[NCLS][LDS_CAP];
  __shared__ int lcnt[NCLS];
  __shared__ int lbase[NCLS];

  if (tid < NCLS) lcnt[tid] = 0;
  __syncthreads();

  const int vbase = chunk * VEC_PER_CHUNK;   // vec4 index within batch
  const float4* p = (const float4*)(cls + (size_t)b * ELEM_PER_BATCH) + vbase;
  for (int i = tid; i < VEC_PER_CHUNK; i += 512) {
    float4 v = p[i];
    float vv[4] = {v.x, v.y, v.z, v.w};
    #pragma unroll
    for (int j = 0; j < 4; ++j) {
      float f = vv[j];
      if (f > T0) {                          // rare (~0.5%)
        int e = (vbase + i) * 4 + j;         // element within batch (< 3M)
        int c = e % NCLS;
        int n = e / NCLS;
        int pos = atomicAdd(&lcnt[c], 1);    // LDS atomic — cheap
        if (pos < LDS_CAP)
          lbuf[c][pos] = ((u64)__float_as_uint(f) << 32) | (unsigned)(~(unsigned)n);
      }
    }
  }
  __syncthreads();

  if (tid < NCLS) {
    int m = lcnt[tid];
    int stored = (m < LDS_CAP) ? m : LDS_CAP;
    int bump = (m > LDS_CAP) ? 1000000 : 0;  // force cnt>CAP -> exact fallback
    int base = atomicAdd(&cnt[b * NCLS + tid], m + bump);
    lbase[tid] = base;
    lcnt[tid] = stored;
  }
  __syncthreads();

  for (int c = 0; c < NCLS; ++c) {
    int m = lcnt[c];
    int base = lbase[c];
    for (int t = tid; t < m; t += 512) {
      int slot = base + t;
      if (slot < CAP)
        coll[(size_t)(b * NCLS + c) * CAP + slot] = lbuf[c][t];
    }
  }
}

// ---------------------------------------------------------------------------
// 2) Exact radix-select fallback for (b,c) with cnt<K or cnt>CAP.
//    Normally a no-op on every block.
// ---------------------------------------------------------------------------
__global__ __launch_bounds__(1024) void fallback_kernel(const float* __restrict__ cls,
                                                        const int* __restrict__ cnt,
                                                        float* __restrict__ ws_s,
                                                        int* __restrict__ ws_i) {
  const int bc = blockIdx.x;
  {
    int ct = cnt[bc];
    if (ct >= K && ct <= CAP) return;   // healthy: handled by fused kernel
  }
  const int b = bc / NCLS, c = bc % NCLS;
  const int tid = threadIdx.x;
  const int nth = blockDim.x;
  const int wv = tid >> 6;

  __shared__ unsigned hist[16][256];
  __shared__ u64 comb[256];
  __shared__ unsigned eqbuf[512];
  __shared__ unsigned s_pref, s_mask, s_krem, s_takeall;
  __shared__ unsigned s_cntgt, s_cnteq;

  if (tid == 0) { s_pref = 0u; s_mask = 0u; s_krem = K; s_takeall = 0u; }
  __syncthreads();
  const float* col = cls + (size_t)b * NBOX * NCLS + c;

  for (int pass = 0; pass < 4; ++pass) {
    if (s_takeall) break;
    const int shift = 24 - 8 * pass;
    for (int i = tid; i < 16 * 256; i += nth) ((unsigned*)hist)[i] = 0u;
    __syncthreads();
    const unsigned pref = s_pref, mask = s_mask;
    for (int n = tid; n < NBOX; n += nth) {
      float v = col[(size_t)n * NCLS];
      if (v > SCORE_THR) {
        unsigned key = __float_as_uint(v);
        if ((key & mask) == pref)
          atomicAdd(&hist[wv][(key >> shift) & 0xFFu], 1u);
      }
    }
    __syncthreads();
    if (tid < 256) {
      unsigned t2 = 0;
      for (int w = 0; w < 16; ++w) t2 += hist[w][tid];
      hist[0][tid] = t2;
    }
    __syncthreads();
    if (tid == 0) {
      unsigned krem = s_krem, cum = 0; int dsel = -1;
      for (int d = 255; d >= 0; --d) {
        unsigned cc = hist[0][d];
        if (cum + cc >= krem) { dsel = d; break; }
        cum += cc;
      }
      if (dsel < 0) s_takeall = 1u;
      else {
        s_krem = krem - cum;
        s_pref = pref | ((unsigned)dsel << shift);
        s_mask = mask | (0xFFu << shift);
      }
    }
    __syncthreads();
  }

  if (tid == 0) { s_cntgt = 0u; s_cnteq = 0u; }
  __syncthreads();
  const unsigned pivot = s_pref;
  const unsigned takeall = s_takeall;

  for (int n = tid; n < NBOX; n += nth) {
    float v = col[(size_t)n * NCLS];
    if (v > SCORE_THR) {
      unsigned key = __float_as_uint(v);
      if (takeall || key > pivot) {
        unsigned pos = atomicAdd(&s_cntgt, 1u);
        if (pos < 256u)
          comb[pos] = ((u64)key << 32) | (unsigned)(~(unsigned)n);
      } else if (key == pivot) {
        unsigned pos = atomicAdd(&s_cnteq, 1u);
        if (pos < 512u) eqbuf[pos] = (unsigned)n;
      }
    }
  }
  __syncthreads();
  const unsigned cntgt = (s_cntgt < 256u) ? s_cntgt : 256u;
  const unsigned cnteq = (s_cnteq < 512u) ? s_cnteq : 512u;
  unsigned need = 0;
  if (!takeall) {
    need = (cntgt < (unsigned)K) ? ((unsigned)K - cntgt) : 0u;
    if (need > cnteq) need = cnteq;
  }
  for (int i = tid; i < 512; i += nth)
    if ((unsigned)i >= cnteq) eqbuf[i] = 0xFFFFFFFFu;
  for (int k = 2; k <= 512; k <<= 1) {
    for (int j = k >> 1; j > 0; j >>= 1) {
      __syncthreads();
      if (tid < 512) {
        int i = tid, l = i ^ j;
        if (l > i) {
          unsigned a = eqbuf[i], bb = eqbuf[l];
          bool up = ((i & k) == 0);
          if (up ? (a > bb) : (a < bb)) { eqbuf[i] = bb; eqbuf[l] = a; }
        }
      }
    }
  }
  __syncthreads();
  for (int t = tid; t < (int)need; t += nth)
    comb[cntgt + t] = ((u64)pivot << 32) | (unsigned)(~eqbuf[t]);
  const unsigned M = cntgt + need;
  for (int i = tid; i < 256; i += nth)
    if ((unsigned)i >= M) comb[i] = 0ull;
  for (int k = 2; k <= 256; k <<= 1) {
    for (int j = k >> 1; j > 0; j >>= 1) {
      __syncthreads();
      if (tid < 256) {
        int i = tid, l = i ^ j;
        if (l > i) {
          u64 a = comb[i], bb = comb[l];
          bool up = ((i & k) == 0);
          if (up ? (a < bb) : (a > bb)) { comb[i] = bb; comb[l] = a; }
        }
      }
    }
  }
  __syncthreads();
  if (tid < K) {
    if ((unsigned)tid < M) {
      u64 e = comb[tid];
      ws_s[bc * K + tid] = __uint_as_float((unsigned)(e >> 32));
      ws_i[bc * K + tid] = (int)(~(unsigned)e);
    } else {
      ws_s[bc * K + tid] = -INFINITY;
      ws_i[bc * K + tid] = 0;
    }
  }
}

// ---------------------------------------------------------------------------
// 3) Fused: sort candidates -> top-200 -> bitmask NMS -> stable compaction ->
//    emit sorted per-class key list (top-128) for the merge tournament.
// ---------------------------------------------------------------------------
__global__ __launch_bounds__(512) void fused_sort_nms_kernel(
    const u64* __restrict__ coll, const int* __restrict__ cnt,
    const float* __restrict__ ws_s_fb, const int* __restrict__ ws_i_fb,
    const float* __restrict__ boxes,
    int* __restrict__ ws_i, u64* __restrict__ merged) {
  const int bc = blockIdx.x;
  const int b = bc / NCLS, c = bc % NCLS;
  const int tid = threadIdx.x;

  __shared__ u64 arr[CAP];
  __shared__ float sx1[K], sy1[K], sx2[K], sy2[K], sarea[K], ss[K];
  __shared__ int sidx[K];
  __shared__ unsigned mask[K][8];
  __shared__ unsigned keepw[8];
  __shared__ int s_surv;

  const int ct = cnt[bc];
  const bool bad = (ct < K) || (ct > CAP);
  if (!bad) {
    for (int i = tid; i < CAP; i += 512)
      arr[i] = (i < ct) ? coll[(size_t)bc * CAP + i] : 0ull;
    for (int k = 2; k <= CAP; k <<= 1) {
      for (int j = k >> 1; j > 0; j >>= 1) {
        __syncthreads();
        for (int i = tid; i < CAP; i += 512) {
          int l = i ^ j;
          if (l > i) {
            u64 a = arr[i], bb = arr[l];
            bool up = ((i & k) == 0);
            if (up ? (a < bb) : (a > bb)) { arr[i] = bb; arr[l] = a; }
          }
        }
      }
    }
    __syncthreads();
    for (int r = tid; r < K; r += 512) {
      u64 e = arr[r];
      float s = (e != 0ull) ? __uint_as_float((unsigned)(e >> 32)) : -INFINITY;
      int idx = (e != 0ull) ? (int)(~(unsigned)e) : 0;
      ss[r] = s; sidx[r] = idx;
      ws_i[bc * K + r] = idx;
    }
  } else {
    for (int r = tid; r < K; r += 512) {
      ss[r] = ws_s_fb[bc * K + r];
      sidx[r] = ws_i_fb[bc * K + r];
    }
  }
  for (int i = tid; i < K * 8; i += 512) ((unsigned*)mask)[i] = 0u;
  if (tid < 8) keepw[tid] = 0u;
  __syncthreads();

  for (int r = tid; r < K; r += 512) {
    float s = ss[r];
    bool valid = (s != -INFINITY);
    float x1 = 0.f, y1 = 0.f, x2 = 0.f, y2 = 0.f;
    if (valid) {
      const float* bp = boxes + ((size_t)b * NBOX + sidx[r]) * 4;
      x1 = bp[0]; y1 = bp[1]; x2 = bp[2]; y2 = bp[3];
      atomicOr(&keepw[r >> 5], 1u << (r & 31));
    }
    sx1[r] = x1; sy1[r] = y1; sx2[r] = x2; sy2[r] = y2;
    sarea[r] = fmaxf(x2 - x1, 0.f) * fmaxf(y2 - y1, 0.f);
  }
  __syncthreads();

  // pairwise suppression bitmask, j > i (fully parallel, no barriers)
  for (int t = tid; t < K * K; t += 512) {
    int i = t / K, j = t - i * K;
    if (j > i) {
      float xx1 = fmaxf(sx1[i], sx1[j]);
      float yy1 = fmaxf(sy1[i], sy1[j]);
      float xx2 = fminf(sx2[i], sx2[j]);
      float yy2 = fminf(sy2[i], sy2[j]);
      float inter = fmaxf(xx2 - xx1, 0.f) * fmaxf(yy2 - yy1, 0.f);
      float uni = sarea[i] + sarea[j] - inter;
      float iou = inter / fmaxf(uni, 1e-8f);
      if (iou > NMS_THR) atomicOr(&mask[i][j >> 5], 1u << (j & 31));
    }
  }
  __syncthreads();

  // serial greedy scan on wave 0 (wave-synchronous, no barriers)
  if (tid < 64) {
    int w = tid & 7;
    unsigned keep = keepw[w];
    for (int i = 0; i < K; ++i) {
      unsigned kw = __shfl(keep, i >> 5, 64);
      if ((kw >> (i & 31)) & 1u)
        keep &= ~mask[i][w];
    }
    if (tid < 8) keepw[tid] = keep;
  }
  __syncthreads();

  // stable compaction + key emission (per-class list is sorted desc by key)
  for (int r = tid; r < K; r += 512) {
    int w6 = r >> 5, bit = r & 31;
    if ((keepw[w6] >> bit) & 1u) {
      int pos = 0;
      #pragma unroll
      for (int w = 0; w < 7; ++w) {
        unsigned kw = keepw[w];
        if (w < w6) pos += __popc(kw);
        else if (w == w6) pos += __popc(kw & ((1u << bit) - 1u));
      }
      if (pos < 128) {
        unsigned ord = __float_as_uint(ss[r]) | 0x80000000u;
        merged[((size_t)b * 32 + c) * 128 + pos] =
          ((u64)ord << 32) | (unsigned)(~(unsigned)(c * K + r));
      }
    }
  }
  if (tid == 0) {
    int S = 0;
    #pragma unroll
    for (int w = 0; w < 7; ++w) S += __popc(keepw[w]);
    s_surv = S;
  }
  __syncthreads();
  for (int t = s_surv + tid; t < 128; t += 512)
    merged[((size_t)b * 32 + c) * 128 + t] = 0ull;
}

// ---------------------------------------------------------------------------
// 4) Per-image merge tournament: 32 sorted lists of 128 -> top-128 -> gather.
// ---------------------------------------------------------------------------
__global__ __launch_bounds__(1024) void merge_gather_kernel(
    const u64* __restrict__ merged, const int* __restrict__ ws_i,
    const float* __restrict__ boxes, const float* __restrict__ rot,
    const float* __restrict__ tr, float* __restrict__ out) {
  const int b = blockIdx.x;
  const int tid = threadIdx.x;
  __shared__ u64 W[4096];

  for (int t = tid; t < 4096; t += 1024) {
    int c = t >> 7, r = t & 127;
    W[t] = (c < NCLS) ? merged[((size_t)b * 32 + c) * 128 + r] : 0ull;
  }
  __syncthreads();

  int active = 4096;
  #pragma unroll
  for (int level = 0; level < 5; ++level) {
    int npairs = active >> 8;
    for (int t = tid; t < npairs * 64; t += 1024) {
      int p = t >> 6, q = t & 63;
      int i1 = p * 256 + 128 + q, i2 = p * 256 + 255 - q;
      u64 a = W[i1]; W[i1] = W[i2]; W[i2] = a;
    }
    __syncthreads();
    for (int j = 128; j > 0; j >>= 1) {
      for (int i = tid; i < active; i += 1024) {
        int l = i ^ j;
        if (l > i) {
          u64 a = W[i], bb = W[l];
          if (a < bb) { W[i] = bb; W[l] = a; }
        }
      }
      __syncthreads();
    }
    int half = active >> 1;
    u64 t0 = 0, t1 = 0;
    if (tid < half) t0 = W[(tid >> 7) * 256 + (tid & 127)];
    int t2i = tid + 1024;
    if (t2i < half) t1 = W[(t2i >> 7) * 256 + (t2i & 127)];
    __syncthreads();
    if (tid < half) W[tid] = t0;
    if (t2i < half) W[t2i] = t1;
    __syncthreads();
    active = half;
  }

  if (tid < MAXDET) {
    u64 key = W[tid];
    bool valid = (key != 0ull);
    float* ob  = out + ((size_t)b * MAXDET + tid) * 4;
    float* os  = out + (size_t)BATCH * MAXDET * 4 + b * MAXDET + tid;
    float* ol  = os + BATCH * MAXDET;
    float* orr = out + (size_t)BATCH * MAXDET * 6 + ((size_t)b * MAXDET + tid) * 3;
    float* ot  = orr + (size_t)BATCH * MAXDET * 3;

    if (valid) {
      unsigned f = ~(unsigned)key;            // flat = c*K + r
      int cl = (int)(f / K);
      float sc = __uint_as_float((unsigned)(key >> 32) & 0x7FFFFFFFu);
      int orig = ws_i[(size_t)b * NCLS * K + f];
      const float* bp = boxes + ((size_t)b * NBOX + orig) * 4;
      ob[0] = bp[0]; ob[1] = bp[1]; ob[2] = bp[2]; ob[3] = bp[3];
      *os = sc;
      *ol = (float)cl;
      const float* rp = rot + ((size_t)b * NBOX + orig) * 3;
      orr[0] = rp[0]; orr[1] = rp[1]; orr[2] = rp[2];
      const float* tp = tr + ((size_t)b * NBOX + orig) * 3;
      ot[0] = tp[0]; ot[1] = tp[1]; ot[2] = tp[2];
    } else {
      ob[0] = ob[1] = ob[2] = ob[3] = -1.f;
      *os = -1.f; *ol = -1.f;
      orr[0] = orr[1] = orr[2] = -1.f;
      ot[0] = ot[1] = ot[2] = -1.f;
    }
  }
}

extern "C" void kernel_launch(void* const* d_in, const int* in_sizes, int n_in,
                              void* d_out, int out_size, void* d_ws, size_t ws_size,
                              hipStream_t stream) {
  const float* boxes = (const float*)d_in[0];
  const float* cls   = (const float*)d_in[1];
  const float* rot   = (const float*)d_in[2];
  const float* tr    = (const float*)d_in[3];
  float* out = (float*)d_out;

  char* ws = (char*)d_ws;
  u64*   coll   = (u64*)(ws + OFF_COLL);
  int*   cnt    = (int*)(ws + OFF_CNT);
  float* ws_s   = (float*)(ws + OFF_WSS);
  int*   ws_i   = (int*)(ws + OFF_WSI);
  u64*   merged = (u64*)(ws + OFF_MERGE);

  init_kernel<<<1, 512, 0, stream>>>(cnt);
  collect_kernel<<<BATCH * CHUNKS, 512, 0, stream>>>(cls, cnt, coll);
  fallback_kernel<<<BATCH * NCLS, 1024, 0, stream>>>(cls, cnt, ws_s, ws_i);
  fused_sort_nms_kernel<<<BATCH * NCLS, 512, 0, stream>>>(coll, cnt, ws_s, ws_i,
                                                          boxes, ws_i, merged);
  merge_gather_kernel<<<BATCH, 1024, 0, stream>>>(merged, ws_i, boxes, rot, tr, out);
}

// Round 6
// 115.986 us; speedup vs baseline: 5.3920x; 1.0511x over previous
//
#include <hip/hip_runtime.h>
#include <math.h>

typedef unsigned long long u64;

#define BATCH 16
#define NBOX 100000
#define NCLS 30
#define K 200            // PRE_NMS_TOPK
#define MAXDET 100
#define SCORE_THR 0.01f
#define NMS_THR 0.5f
#define T0 0.995f        // static collect threshold; inline fallback guarantees exactness

#define ELEM_PER_BATCH (NBOX * NCLS)              // 3,000,000
#define CAP 1024
#define CHUNKS 48                                 // chunks per batch
#define VEC_PER_CHUNK 15625                       // 750000 vec4 per batch / 48
#define LDS_CAP 48                                // per-class per-block hit buffer

// workspace layout (bytes)
#define OFF_COLL   0ull                                            // u64[480*CAP]
#define OFF_CNT    (OFF_COLL + (size_t)BATCH*NCLS*CAP*8)           // int[480] (+pad)
#define OFF_WSI    (OFF_CNT + 512*4)                               // int[480*200]
#define OFF_MERGE  (OFF_WSI + (size_t)BATCH*NCLS*K*4)              // u64[16][32][128]

// ---------------------------------------------------------------------------
// 1) Single coalesced pass: collect entries > T0. Hits staged in per-class
//    LDS buffers (LDS atomics only); ONE global atomicAdd per (class,block)
//    reserves a contiguous segment of coll. Hot loop: 1 load + 3 fmax + 1 cmp.
// ---------------------------------------------------------------------------
__global__ __launch_bounds__(512) void collect_kernel(const float* __restrict__ cls,
                                                      int* __restrict__ cnt,
                                                      u64* __restrict__ coll) {
  const int b = blockIdx.x / CHUNKS;
  const int chunk = blockIdx.x % CHUNKS;
  const int tid = threadIdx.x;

  __shared__ u64 lbuf[NCLS][LDS_CAP];
  __shared__ int lcnt[NCLS];
  __shared__ int lbase[NCLS];

  if (tid < NCLS) lcnt[tid] = 0;
  __syncthreads();

  const int vbase = chunk * VEC_PER_CHUNK;   // vec4 index within batch
  const float4* p = (const float4*)(cls + (size_t)b * ELEM_PER_BATCH) + vbase;
  for (int i = tid; i < VEC_PER_CHUNK; i += 512) {
    float4 v = p[i];
    float m = fmaxf(fmaxf(v.x, v.y), fmaxf(v.z, v.w));
    if (m > T0) {                            // rare (~2% of vec4s)
      float vv[4] = {v.x, v.y, v.z, v.w};
      #pragma unroll
      for (int j = 0; j < 4; ++j) {
        float f = vv[j];
        if (f > T0) {
          int e = (vbase + i) * 4 + j;       // element within batch (< 3M)
          int c = e % NCLS;
          int n = e / NCLS;
          int pos = atomicAdd(&lcnt[c], 1);  // LDS atomic — cheap
          if (pos < LDS_CAP)
            lbuf[c][pos] = ((u64)__float_as_uint(f) << 32) | (unsigned)(~(unsigned)n);
        }
      }
    }
  }
  __syncthreads();

  if (tid < NCLS) {
    int m = lcnt[tid];
    int stored = (m < LDS_CAP) ? m : LDS_CAP;
    int bump = (m > LDS_CAP) ? 1000000 : 0;  // force cnt>CAP -> exact fallback path
    int base = atomicAdd(&cnt[b * NCLS + tid], m + bump);
    lbase[tid] = base;
    lcnt[tid] = stored;
  }
  __syncthreads();

  // parallel flush over all (class, slot) pairs: 1440 / 512 = 3 iterations
  for (int t = tid; t < NCLS * LDS_CAP; t += 512) {
    int c = t / LDS_CAP, s = t - (t / LDS_CAP) * LDS_CAP;
    if (s < lcnt[c]) {
      int slot = lbase[c] + s;
      if (slot < CAP)
        coll[(size_t)(b * NCLS + c) * CAP + slot] = lbuf[c][s];
    }
  }
}

// ---------------------------------------------------------------------------
// 2) Fused: sort candidates -> top-200 -> bitmask NMS -> stable compaction ->
//    emit sorted per-class key list (top-128) for the merge tournament.
//    Bad (b,c) [cnt<K or cnt>CAP]: inline exact radix-select from cls.
// ---------------------------------------------------------------------------
__global__ __launch_bounds__(512) void fused_sort_nms_kernel(
    const u64* __restrict__ coll, const int* __restrict__ cnt,
    const float* __restrict__ cls, const float* __restrict__ boxes,
    int* __restrict__ ws_i, u64* __restrict__ merged) {
  const int bc = blockIdx.x;
  const int b = bc / NCLS, c = bc % NCLS;
  const int tid = threadIdx.x;

  __shared__ u64 arr[CAP];                 // good path: sort buffer; bad path: hist overlay
  __shared__ float sx1[K], sy1[K], sx2[K], sy2[K], sarea[K], ss[K];
  __shared__ int sidx[K];
  __shared__ unsigned mask[K][8];
  __shared__ unsigned keepw[8];
  __shared__ int s_surv;
  __shared__ u64 comb[256];
  __shared__ unsigned eqbuf[512];
  __shared__ unsigned s_pref, s_mask, s_krem, s_takeall;
  __shared__ unsigned s_cntgt, s_cnteq;

  const int ct = cnt[bc];
  const bool bad = (ct < K) || (ct > CAP);
  if (!bad) {
    for (int i = tid; i < CAP; i += 512)
      arr[i] = (i < ct) ? coll[(size_t)bc * CAP + i] : 0ull;
    for (int k = 2; k <= CAP; k <<= 1) {
      for (int j = k >> 1; j > 0; j >>= 1) {
        __syncthreads();
        for (int i = tid; i < CAP; i += 512) {
          int l = i ^ j;
          if (l > i) {
            u64 a = arr[i], bb = arr[l];
            bool up = ((i & k) == 0);
            if (up ? (a < bb) : (a > bb)) { arr[i] = bb; arr[l] = a; }
          }
        }
      }
    }
    __syncthreads();
    for (int r = tid; r < K; r += 512) {
      u64 e = arr[r];
      float s = (e != 0ull) ? __uint_as_float((unsigned)(e >> 32)) : -INFINITY;
      int idx = (e != 0ull) ? (int)(~(unsigned)e) : 0;
      ss[r] = s; sidx[r] = idx;
      ws_i[bc * K + r] = idx;
    }
  } else {
    // ---- inline exact radix select over the strided class column ----
    unsigned (*hist)[256] = (unsigned (*)[256])arr;   // 8 waves x 256 bins = 8KB
    const int wv = tid >> 6;
    if (tid == 0) { s_pref = 0u; s_mask = 0u; s_krem = K; s_takeall = 0u; }
    __syncthreads();
    const float* col = cls + (size_t)b * NBOX * NCLS + c;

    for (int pass = 0; pass < 4; ++pass) {
      if (s_takeall) break;
      const int shift = 24 - 8 * pass;
      for (int i = tid; i < 8 * 256; i += 512) ((unsigned*)hist)[i] = 0u;
      __syncthreads();
      const unsigned pref = s_pref, msk = s_mask;
      for (int n = tid; n < NBOX; n += 512) {
        float v = col[(size_t)n * NCLS];
        if (v > SCORE_THR) {
          unsigned key = __float_as_uint(v);
          if ((key & msk) == pref)
            atomicAdd(&hist[wv][(key >> shift) & 0xFFu], 1u);
        }
      }
      __syncthreads();
      if (tid < 256) {
        unsigned t2 = 0;
        for (int w = 0; w < 8; ++w) t2 += hist[w][tid];
        hist[0][tid] = t2;
      }
      __syncthreads();
      if (tid == 0) {
        unsigned krem = s_krem, cum = 0; int dsel = -1;
        for (int d = 255; d >= 0; --d) {
          unsigned cc = hist[0][d];
          if (cum + cc >= krem) { dsel = d; break; }
          cum += cc;
        }
        if (dsel < 0) s_takeall = 1u;
        else {
          s_krem = krem - cum;
          s_pref = pref | ((unsigned)dsel << shift);
          s_mask = msk | (0xFFu << shift);
        }
      }
      __syncthreads();
    }

    if (tid == 0) { s_cntgt = 0u; s_cnteq = 0u; }
    __syncthreads();
    const unsigned pivot = s_pref;
    const unsigned takeall = s_takeall;

    for (int n = tid; n < NBOX; n += 512) {
      float v = col[(size_t)n * NCLS];
      if (v > SCORE_THR) {
        unsigned key = __float_as_uint(v);
        if (takeall || key > pivot) {
          unsigned pos = atomicAdd(&s_cntgt, 1u);
          if (pos < 256u)
            comb[pos] = ((u64)key << 32) | (unsigned)(~(unsigned)n);
        } else if (key == pivot) {
          unsigned pos = atomicAdd(&s_cnteq, 1u);
          if (pos < 512u) eqbuf[pos] = (unsigned)n;
        }
      }
    }
    __syncthreads();
    const unsigned cntgt = (s_cntgt < 256u) ? s_cntgt : 256u;
    const unsigned cnteq = (s_cnteq < 512u) ? s_cnteq : 512u;
    unsigned need = 0;
    if (!takeall) {
      need = (cntgt < (unsigned)K) ? ((unsigned)K - cntgt) : 0u;
      if (need > cnteq) need = cnteq;
    }
    for (int i = tid; i < 512; i += 512)
      if ((unsigned)i >= cnteq) eqbuf[i] = 0xFFFFFFFFu;
    for (int k = 2; k <= 512; k <<= 1) {
      for (int j = k >> 1; j > 0; j >>= 1) {
        __syncthreads();
        {
          int i = tid, l = i ^ j;
          if (l > i) {
            unsigned a = eqbuf[i], bb = eqbuf[l];
            bool up = ((i & k) == 0);
            if (up ? (a > bb) : (a < bb)) { eqbuf[i] = bb; eqbuf[l] = a; }
          }
        }
      }
    }
    __syncthreads();
    for (int t = tid; t < (int)need; t += 512)
      comb[cntgt + t] = ((u64)pivot << 32) | (unsigned)(~eqbuf[t]);
    const unsigned M = cntgt + need;
    for (int i = tid; i < 256; i += 512)
      if ((unsigned)i >= M) comb[i] = 0ull;
    for (int k = 2; k <= 256; k <<= 1) {
      for (int j = k >> 1; j > 0; j >>= 1) {
        __syncthreads();
        if (tid < 256) {
          int i = tid, l = i ^ j;
          if (l > i) {
            u64 a = comb[i], bb = comb[l];
            bool up = ((i & k) == 0);
            if (up ? (a < bb) : (a > bb)) { comb[i] = bb; comb[l] = a; }
          }
        }
      }
    }
    __syncthreads();
    if (tid < K) {
      if ((unsigned)tid < M) {
        u64 e = comb[tid];
        ss[tid] = __uint_as_float((unsigned)(e >> 32));
        sidx[tid] = (int)(~(unsigned)e);
      } else {
        ss[tid] = -INFINITY;
        sidx[tid] = 0;
      }
      ws_i[bc * K + tid] = sidx[tid];
    }
  }
  for (int i = tid; i < K * 8; i += 512) ((unsigned*)mask)[i] = 0u;
  if (tid < 8) keepw[tid] = 0u;
  __syncthreads();

  for (int r = tid; r < K; r += 512) {
    float s = ss[r];
    bool valid = (s != -INFINITY);
    float x1 = 0.f, y1 = 0.f, x2 = 0.f, y2 = 0.f;
    if (valid) {
      const float* bp = boxes + ((size_t)b * NBOX + sidx[r]) * 4;
      x1 = bp[0]; y1 = bp[1]; x2 = bp[2]; y2 = bp[3];
      atomicOr(&keepw[r >> 5], 1u << (r & 31));
    }
    sx1[r] = x1; sy1[r] = y1; sx2[r] = x2; sy2[r] = y2;
    sarea[r] = fmaxf(x2 - x1, 0.f) * fmaxf(y2 - y1, 0.f);
  }
  __syncthreads();

  // pairwise suppression bitmask, j > i (fully parallel, no barriers)
  for (int t = tid; t < K * K; t += 512) {
    int i = t / K, j = t - i * K;
    if (j > i) {
      float xx1 = fmaxf(sx1[i], sx1[j]);
      float yy1 = fmaxf(sy1[i], sy1[j]);
      float xx2 = fminf(sx2[i], sx2[j]);
      float yy2 = fminf(sy2[i], sy2[j]);
      float inter = fmaxf(xx2 - xx1, 0.f) * fmaxf(yy2 - yy1, 0.f);
      float uni = sarea[i] + sarea[j] - inter;
      float iou = inter / fmaxf(uni, 1e-8f);
      if (iou > NMS_THR) atomicOr(&mask[i][j >> 5], 1u << (j & 31));
    }
  }
  __syncthreads();

  // serial greedy scan on wave 0 (wave-synchronous, no barriers)
  if (tid < 64) {
    int w = tid & 7;
    unsigned keep = keepw[w];
    for (int i = 0; i < K; ++i) {
      unsigned kw = __shfl(keep, i >> 5, 64);
      if ((kw >> (i & 31)) & 1u)
        keep &= ~mask[i][w];
    }
    if (tid < 8) keepw[tid] = keep;
  }
  __syncthreads();

  // stable compaction + key emission (per-class list is sorted desc by key)
  for (int r = tid; r < K; r += 512) {
    int w6 = r >> 5, bit = r & 31;
    if ((keepw[w6] >> bit) & 1u) {
      int pos = 0;
      #pragma unroll
      for (int w = 0; w < 7; ++w) {
        unsigned kw = keepw[w];
        if (w < w6) pos += __popc(kw);
        else if (w == w6) pos += __popc(kw & ((1u << bit) - 1u));
      }
      if (pos < 128) {
        unsigned ord = __float_as_uint(ss[r]) | 0x80000000u;
        merged[((size_t)b * 32 + c) * 128 + pos] =
          ((u64)ord << 32) | (unsigned)(~(unsigned)(c * K + r));
      }
    }
  }
  if (tid == 0) {
    int S = 0;
    #pragma unroll
    for (int w = 0; w < 7; ++w) S += __popc(keepw[w]);
    s_surv = S;
  }
  __syncthreads();
  for (int t = s_surv + tid; t < 128; t += 512)
    merged[((size_t)b * 32 + c) * 128 + t] = 0ull;
}

// ---------------------------------------------------------------------------
// 3) Per-image merge tournament: 32 sorted lists of 128 -> top-128 -> gather.
// ---------------------------------------------------------------------------
__global__ __launch_bounds__(1024) void merge_gather_kernel(
    const u64* __restrict__ merged, const int* __restrict__ ws_i,
    const float* __restrict__ boxes, const float* __restrict__ rot,
    const float* __restrict__ tr, float* __restrict__ out) {
  const int b = blockIdx.x;
  const int tid = threadIdx.x;
  __shared__ u64 W[4096];

  for (int t = tid; t < 4096; t += 1024) {
    int c = t >> 7, r = t & 127;
    W[t] = (c < NCLS) ? merged[((size_t)b * 32 + c) * 128 + r] : 0ull;
  }
  __syncthreads();

  int active = 4096;
  #pragma unroll
  for (int level = 0; level < 5; ++level) {
    int npairs = active >> 8;
    for (int t = tid; t < npairs * 64; t += 1024) {
      int p = t >> 6, q = t & 63;
      int i1 = p * 256 + 128 + q, i2 = p * 256 + 255 - q;
      u64 a = W[i1]; W[i1] = W[i2]; W[i2] = a;
    }
    __syncthreads();
    for (int j = 128; j > 0; j >>= 1) {
      for (int i = tid; i < active; i += 1024) {
        int l = i ^ j;
        if (l > i) {
          u64 a = W[i], bb = W[l];
          if (a < bb) { W[i] = bb; W[l] = a; }
        }
      }
      __syncthreads();
    }
    int half = active >> 1;
    u64 t0 = 0, t1 = 0;
    if (tid < half) t0 = W[(tid >> 7) * 256 + (tid & 127)];
    int t2i = tid + 1024;
    if (t2i < half) t1 = W[(t2i >> 7) * 256 + (t2i & 127)];
    __syncthreads();
    if (tid < half) W[tid] = t0;
    if (t2i < half) W[t2i] = t1;
    __syncthreads();
    active = half;
  }

  if (tid < MAXDET) {
    u64 key = W[tid];
    bool valid = (key != 0ull);
    float* ob  = out + ((size_t)b * MAXDET + tid) * 4;
    float* os  = out + (size_t)BATCH * MAXDET * 4 + b * MAXDET + tid;
    float* ol  = os + BATCH * MAXDET;
    float* orr = out + (size_t)BATCH * MAXDET * 6 + ((size_t)b * MAXDET + tid) * 3;
    float* ot  = orr + (size_t)BATCH * MAXDET * 3;

    if (valid) {
      unsigned f = ~(unsigned)key;            // flat = c*K + r
      int cl = (int)(f / K);
      float sc = __uint_as_float((unsigned)(key >> 32) & 0x7FFFFFFFu);
      int orig = ws_i[(size_t)b * NCLS * K + f];
      const float* bp = boxes + ((size_t)b * NBOX + orig) * 4;
      ob[0] = bp[0]; ob[1] = bp[1]; ob[2] = bp[2]; ob[3] = bp[3];
      *os = sc;
      *ol = (float)cl;
      const float* rp = rot + ((size_t)b * NBOX + orig) * 3;
      orr[0] = rp[0]; orr[1] = rp[1]; orr[2] = rp[2];
      const float* tp = tr + ((size_t)b * NBOX + orig) * 3;
      ot[0] = tp[0]; ot[1] = tp[1]; ot[2] = tp[2];
    } else {
      ob[0] = ob[1] = ob[2] = ob[3] = -1.f;
      *os = -1.f; *ol = -1.f;
      orr[0] = orr[1] = orr[2] = -1.f;
      ot[0] = ot[1] = ot[2] = -1.f;
    }
  }
}

extern "C" void kernel_launch(void* const* d_in, const int* in_sizes, int n_in,
                              void* d_out, int out_size, void* d_ws, size_t ws_size,
                              hipStream_t stream) {
  const float* boxes = (const float*)d_in[0];
  const float* cls   = (const float*)d_in[1];
  const float* rot   = (const float*)d_in[2];
  const float* tr    = (const float*)d_in[3];
  float* out = (float*)d_out;

  char* ws = (char*)d_ws;
  u64*   coll   = (u64*)(ws + OFF_COLL);
  int*   cnt    = (int*)(ws + OFF_CNT);
  int*   ws_i   = (int*)(ws + OFF_WSI);
  u64*   merged = (u64*)(ws + OFF_MERGE);

  hipMemsetAsync(cnt, 0, BATCH * NCLS * sizeof(int), stream);
  collect_kernel<<<BATCH * CHUNKS, 512, 0, stream>>>(cls, cnt, coll);
  fused_sort_nms_kernel<<<BATCH * NCLS, 512, 0, stream>>>(coll, cnt, cls, boxes,
                                                          ws_i, merged);
  merge_gather_kernel<<<BATCH, 1024, 0, stream>>>(merged, ws_i, boxes, rot, tr, out);
}